// Round 13
// baseline (3617.027 us; speedup 1.0000x reference)
//
#include <hip/hip_runtime.h>
#include <hip/hip_bf16.h>

#define T_ 256
#define B_ 64
#define NWG 32      // recurrence WGs: each owns 16 h-dims

typedef __attribute__((ext_vector_type(8))) short bf16x8;
typedef __attribute__((ext_vector_type(4))) float f32x4;
typedef __attribute__((ext_vector_type(4))) unsigned uint4v;
union v128 { uint4v u4; bf16x8 h8; };

__device__ __forceinline__ float bf2f(unsigned short u){
  unsigned int i = ((unsigned int)u) << 16;
  float f; __builtin_memcpy(&f, &i, 4); return f;
}
__device__ __forceinline__ unsigned short f2bf(float f){
  __hip_bfloat16 h = __float2bfloat16(f);
  unsigned short u; __builtin_memcpy(&u, &h, 2); return u;
}
__device__ __forceinline__ float fsigm(float x){ return 1.0f/(1.0f + __expf(-x)); }
__device__ __forceinline__ float ftanh(float x){ return 1.0f - 2.0f/(__expf(2.0f*x) + 1.0f); }

// MALL-coherent plain accessors (sc0 sc1 = bypass L1+L2)
__device__ __forceinline__ unsigned long long ld8_cc(const void* p){
  unsigned long long v;
  asm volatile("global_load_dwordx2 %0, %1, off sc0 sc1\n\ts_waitcnt vmcnt(0)"
               : "=v"(v) : "v"(p) : "memory");
  return v;
}
// gen-stamped 16B block store: {h0h1, h2h3, gen, 0} — one line, applied atomically
__device__ __forceinline__ void st_blk(void* base, int p, int b, int kb,
                                       unsigned d01, unsigned d23, unsigned gen){
  uint4v v; v[0]=d01; v[1]=d23; v[2]=gen; v[3]=0u;
  void* addr = (char*)base + ((((size_t)p*64 + b)*128 + kb)<<4);
  asm volatile("global_store_dwordx4 %0, %1, off sc0 sc1" :: "v"(addr), "v"(v) : "memory");
}

#define LD4(dst, off) asm volatile("global_load_dwordx4 %0, %1, off offset:" #off " sc0 sc1" \
                                   : "=v"(dst) : "v"(ab) : "memory")

// fused poll+read: 32 gen-stamped blocks (this lane's MFMA A-fragment source).
// Retries until every embedded gen >= need. Single round trip in steady state.
__device__ __forceinline__ void poll_read(const char* ab, unsigned need, v128 blk[16][2]){
  for(;;){
    LD4(blk[0][0].u4, 0);     LD4(blk[0][1].u4, 16);
    LD4(blk[1][0].u4, 128);   LD4(blk[1][1].u4, 144);
    LD4(blk[2][0].u4, 256);   LD4(blk[2][1].u4, 272);
    LD4(blk[3][0].u4, 384);   LD4(blk[3][1].u4, 400);
    LD4(blk[4][0].u4, 512);   LD4(blk[4][1].u4, 528);
    LD4(blk[5][0].u4, 640);   LD4(blk[5][1].u4, 656);
    LD4(blk[6][0].u4, 768);   LD4(blk[6][1].u4, 784);
    LD4(blk[7][0].u4, 896);   LD4(blk[7][1].u4, 912);
    LD4(blk[8][0].u4, 1024);  LD4(blk[8][1].u4, 1040);
    LD4(blk[9][0].u4, 1152);  LD4(blk[9][1].u4, 1168);
    LD4(blk[10][0].u4, 1280); LD4(blk[10][1].u4, 1296);
    LD4(blk[11][0].u4, 1408); LD4(blk[11][1].u4, 1424);
    LD4(blk[12][0].u4, 1536); LD4(blk[12][1].u4, 1552);
    LD4(blk[13][0].u4, 1664); LD4(blk[13][1].u4, 1680);
    LD4(blk[14][0].u4, 1792); LD4(blk[14][1].u4, 1808);
    LD4(blk[15][0].u4, 1920); LD4(blk[15][1].u4, 1936);
    asm volatile("s_waitcnt vmcnt(0)" ::: "memory");
    bool ok = true;
    #pragma unroll
    for (int ks=0;ks<16;ks++)
      ok = ok && (blk[ks][0].u4[2] >= need) && (blk[ks][1].u4[2] >= need);
    if (__ballot(ok) == ~0ull) break;
    __builtin_amdgcn_s_sleep(1);
  }
  __builtin_amdgcn_sched_barrier(0);
}

// ---------------- prep ----------------
__global__ void k_prep(const int* __restrict__ in0, const int* __restrict__ in1,
                       const int* __restrict__ mtok,
                       const float* __restrict__ emb0, const float* __restrict__ emb1,
                       const float* __restrict__ Wih_low, const float* __restrict__ Whh_low_f,
                       const float* __restrict__ Wih_high_f, const float* __restrict__ Whh_high_f,
                       const float* __restrict__ Wdec0_f, const float* __restrict__ Wdec1_f,
                       unsigned short* __restrict__ W0, unsigned short* __restrict__ Wlh,
                       unsigned short* __restrict__ Whhl, unsigned short* __restrict__ Wihh,
                       unsigned short* __restrict__ Whhh, unsigned short* __restrict__ Wd0,
                       unsigned short* __restrict__ Wd1, unsigned short* __restrict__ E,
                       float* __restrict__ mask, unsigned* __restrict__ stepflag,
                       unsigned* __restrict__ bar,
                       uint4v* __restrict__ hlP, uint4v* __restrict__ hhP)
{
  int gid = blockIdx.x*blockDim.x + threadIdx.x;
  int gsz = gridDim.x*blockDim.x;
  for (int i=gid; i<2048*512; i+=gsz){
    int r = i>>9, c = i&511;
    W0[i]   = f2bf(Wih_low[(size_t)r*1024 + c]);
    Wlh[i]  = f2bf(Wih_low[(size_t)r*1024 + 512 + c]);
    Whhl[i] = f2bf(Whh_low_f[i]);
    Wihh[i] = f2bf(Wih_high_f[i]);
    Whhh[i] = f2bf(Whh_high_f[i]);
    Wd0[i]  = f2bf(Wdec0_f[i]);
  }
  for (int i=gid; i<512*512; i+=gsz) Wd1[i] = f2bf(Wdec1_f[i]);
  int mt = mtok[0];
  for (int i=gid; i<T_*B_*512; i+=gsz){
    int m = i>>9, k = i&511;
    int t = m>>6, b = m&63;
    float v;
    if (k < 256) v = emb0[(size_t)in0[b*T_+t]*256 + k];
    else         v = emb1[(size_t)in1[b*T_+t]*256 + (k-256)];
    E[i] = f2bf(v);
  }
  for (int i=gid; i<T_*B_; i+=gsz){
    int t = i>>6, b = i&63;
    mask[i] = (in0[b*T_+t] == mt) ? 1.0f : 0.0f;
  }
  for (int i=gid; i<T_; i+=gsz){
    unsigned f = 0;
    for (int b=0;b<B_;b++) f |= (in0[b*T_+i] == mt) ? 1u : 0u;
    stepflag[i] = f;
  }
  for (int i=gid; i<1024; i+=gsz) bar[i] = 0;
  // zero gen-stamped h buffers (both parities) — replays don't re-poison ws
  uint4v z; z[0]=0u; z[1]=0u; z[2]=0u; z[3]=0u;
  for (int i=gid; i<2*64*128; i+=gsz){ hlP[i] = z; hhP[i] = z; }
}

// ---------------- bf16 MFMA GEMM: out[M,N] = A[M,512] @ W[N,512]^T + bias ----------------
__launch_bounds__(256)
__global__ void k_gemm(const unsigned short* __restrict__ A,
                       const unsigned short* __restrict__ W,
                       const float* __restrict__ bias1, const float* __restrict__ bias2,
                       unsigned short* __restrict__ out16, float* __restrict__ out32,
                       int N, int mode)
{
  __shared__ unsigned short As[128*40];
  __shared__ unsigned short Bs[128*40];
  const int tid = threadIdx.x;
  const int m0 = blockIdx.x*128, n0 = blockIdx.y*128;
  const int wid = tid>>6, lane = tid&63;
  const int wm = (wid>>1)*64, wn = (wid&1)*64;
  const int lr = lane&15, lk = lane>>4;
  f32x4 acc[4][4] = {};
  for (int k0=0; k0<512; k0+=32){
    __syncthreads();
    #pragma unroll
    for (int i=0;i<2;i++){
      int eb = tid + 256*i;
      int row = eb>>2, kb = eb&3;
      *(bf16x8*)&As[row*40 + kb*8] = *(const bf16x8*)&A[(size_t)(m0+row)*512 + k0 + kb*8];
      *(bf16x8*)&Bs[row*40 + kb*8] = *(const bf16x8*)&W[(size_t)(n0+row)*512 + k0 + kb*8];
    }
    __syncthreads();
    bf16x8 af[4], bff[4];
    #pragma unroll
    for (int i=0;i<4;i++){
      af[i]  = *(const bf16x8*)&As[(wm + i*16 + lr)*40 + lk*8];
      bff[i] = *(const bf16x8*)&Bs[(wn + i*16 + lr)*40 + lk*8];
    }
    #pragma unroll
    for (int mi=0;mi<4;mi++)
      #pragma unroll
      for (int ni=0;ni<4;ni++)
        acc[mi][ni] = __builtin_amdgcn_mfma_f32_16x16x32_bf16(af[mi], bff[ni], acc[mi][ni], 0,0,0);
  }
  #pragma unroll
  for (int mi=0;mi<4;mi++){
    #pragma unroll
    for (int ni=0;ni<4;ni++){
      int n = n0 + wn + ni*16 + lr;
      float bb = bias1 ? bias1[n] : 0.0f;
      if (bias2) bb += bias2[n];
      #pragma unroll
      for (int r=0;r<4;r++){
        int m = m0 + wm + mi*16 + lk*4 + r;
        float v = acc[mi][ni][r] + bb;
        if (mode == 0){
          out16[(size_t)m*N + n] = f2bf(v);
        } else {
          int t = m>>6, b = m&63;
          out32[((size_t)b*T_ + t)*N + n] = v;
        }
      }
    }
  }
}

// ------- one-time init barrier (r9-verified flag scheme) -------
__device__ __forceinline__ void g_arrive(unsigned* flags, int j){
  asm volatile("s_waitcnt vmcnt(0)" ::: "memory");
  __syncthreads();
  if (threadIdx.x == 0)
    __hip_atomic_store(&flags[j*32], 1u, __ATOMIC_RELAXED, __HIP_MEMORY_SCOPE_AGENT);
  __builtin_amdgcn_sched_barrier(0);
}
__device__ __forceinline__ void g_wait(const unsigned* flags){
  if (threadIdx.x < 64){
    const unsigned* fp = &flags[(threadIdx.x & (NWG-1))*32];
    for(;;){
      unsigned v = __hip_atomic_load(fp, __ATOMIC_RELAXED, __HIP_MEMORY_SCOPE_AGENT);
      if (__ballot(v >= 1u) == ~0ull) break;
      __builtin_amdgcn_s_sleep(1);
    }
  }
  __builtin_amdgcn_sched_barrier(0);
  __syncthreads();
  __builtin_amdgcn_sched_barrier(0);
}

// ---------------- persistent recurrence: 32 WGs, WG j owns h-dims [16j, 16j+16) ----------------
__launch_bounds__(256)
__global__ void k_recur(const float* __restrict__ h_low0, const float* __restrict__ c_low0,
                        const float* __restrict__ h_high0, const float* __restrict__ c_high0,
                        const float* __restrict__ bih_high, const float* __restrict__ bhh_high,
                        const unsigned short* __restrict__ xW,
                        const unsigned short* __restrict__ Whhl,
                        const unsigned short* __restrict__ Wlh,
                        const unsigned short* __restrict__ Wihh,
                        const unsigned short* __restrict__ Whhh,
                        const float* __restrict__ mask, const unsigned* __restrict__ stepflag,
                        char* __restrict__ hlP, char* __restrict__ hhP,
                        unsigned short* __restrict__ hseq, unsigned* bar,
                        float* __restrict__ outS)
{
  __shared__ unsigned short Ws[64*520];   // Whh_low slice (64 gate rows), LDS-resident
  __shared__ float hht[64*68];
  __shared__ float gb[64*68];
  __shared__ float cl[64*16];
  __shared__ float ch[64*16];
  const int tid = threadIdx.x;
  const int j = blockIdx.x;
  const int d0 = j*16;
  const int wid = tid>>6, lane = tid&63;
  const int lr = lane&15, lk = lane>>4;
  const int mb = wid*16;
  const int eb = tid>>2;            // elementwise batch (in wave's [mb,mb+16) range)
  const int eq = tid&3;             // block index within WG's 4 blocks
  const int ep = eq*4;              // 4 dims per thread
  const int kb = j*4 + eq;          // this thread's gen-stamped block column

  for (int i=tid; i<64*64; i+=256){
    int n = i>>6, cb = i&63;
    int grow = (n>>4)*512 + d0 + (n&15);
    *(bf16x8*)&Ws[n*520 + cb*8] = *(const bf16x8*)&Whhl[(size_t)grow*512 + cb*8];
  }
  for (int i=tid; i<1024; i+=256){
    int b=i>>4, dd=i&15;
    cl[i] = c_low0[b*512 + d0 + dd];
    ch[i] = c_high0[b*512 + d0 + dd];
  }
  {
    int gi = eb*512 + d0 + ep;
    unsigned l01 = (unsigned)f2bf(h_low0[gi])   | ((unsigned)f2bf(h_low0[gi+1])<<16);
    unsigned l23 = (unsigned)f2bf(h_low0[gi+2]) | ((unsigned)f2bf(h_low0[gi+3])<<16);
    unsigned h01 = (unsigned)f2bf(h_high0[gi])  | ((unsigned)f2bf(h_high0[gi+1])<<16);
    unsigned h23 = (unsigned)f2bf(h_high0[gi+2])| ((unsigned)f2bf(h_high0[gi+3])<<16);
    st_blk(hlP, 0, eb, kb, l01, l23, 0u);
    st_blk(hhP, 0, eb, kb, h01, h23, 0u);
  }
  g_arrive(bar, j);                 // init data certified at MALL (covers trivial t=0 polls)
  g_wait(bar);

  // per-lane byte offsets of the 32-block read window (row = mb+lr, blocks lk*2 + ks*8 + {0,1})
  const size_t rowoff = ((size_t)(mb+lr)*128 + lk*2) << 4;
  const size_t paroff = (size_t)64*128*16;   // parity stride in bytes

  // prefetch xW(t=0)
  unsigned long long cxi, cxf, cxg, cxo, nxi, nxf, nxg, nxo;
  {
    size_t xr = (size_t)eb*2048 + d0 + ep;
    cxi = *(const unsigned long long*)&xW[xr];
    cxf = *(const unsigned long long*)&xW[xr + 512];
    cxg = *(const unsigned long long*)&xW[xr + 1024];
    cxo = *(const unsigned long long*)&xW[xr + 1536];
  }
  // initial hht from hh parity 0 (need 0 — trivially passes, data valid post-barrier)
  v128 blk[16][2];
  {
    poll_read(hhP + rowoff, 0u, blk);
    f32x4 a[4] = {};
    #pragma unroll
    for (int ks=0;ks<16;ks++){
      v128 u; u.u4[0]=blk[ks][0].u4[0]; u.u4[1]=blk[ks][0].u4[1];
              u.u4[2]=blk[ks][1].u4[0]; u.u4[3]=blk[ks][1].u4[1];
      #pragma unroll
      for (int g=0; g<4; g++){
        bf16x8 bg = *(const bf16x8*)&Wlh[(size_t)(g*512 + d0 + lr)*512 + ks*32 + lk*8];
        a[g] = __builtin_amdgcn_mfma_f32_16x16x32_bf16(u.h8, bg, a[g], 0,0,0);
      }
    }
    #pragma unroll
    for (int g=0; g<4; g++)
      #pragma unroll
      for (int r=0;r<4;r++) hht[(mb + lk*4 + r)*68 + g*16 + lr] = a[g][r];
  }

  int hs = 0;
  unsigned hhneed = 0;
  for (int t=0; t<T_; t++){
    const int rl = t&1, wl = rl^1;
    // ---- phase A: poll+read h(t-1) [gen >= t], then low-cell gates ----
    poll_read(hlP + (size_t)rl*paroff + rowoff, (unsigned)t, blk);
    // prefetch next step's xW (completes under MFMAs, consumed at t+1)
    if (t+1 < T_){
      size_t xr = ((size_t)(t+1)*64 + eb)*2048 + d0 + ep;
      nxi = *(const unsigned long long*)&xW[xr];
      nxf = *(const unsigned long long*)&xW[xr + 512];
      nxg = *(const unsigned long long*)&xW[xr + 1024];
      nxo = *(const unsigned long long*)&xW[xr + 1536];
    }
    f32x4 a[4] = {};
    #pragma unroll
    for (int ks=0;ks<16;ks++){
      v128 u; u.u4[0]=blk[ks][0].u4[0]; u.u4[1]=blk[ks][0].u4[1];
              u.u4[2]=blk[ks][1].u4[0]; u.u4[3]=blk[ks][1].u4[1];
      #pragma unroll
      for (int g=0; g<4; g++){
        bf16x8 bg = *(const bf16x8*)&Ws[(g*16+lr)*520 + ks*32 + lk*8];
        a[g] = __builtin_amdgcn_mfma_f32_16x16x32_bf16(u.h8, bg, a[g], 0,0,0);
      }
    }
    #pragma unroll
    for (int g=0; g<4; g++)
      #pragma unroll
      for (int r=0;r<4;r++){
        int b = mb + lk*4 + r;
        gb[b*68 + g*16 + lr] = a[g][r] + hht[b*68 + g*16 + lr];
      }
    // elementwise (wave-local rows; wave lockstep — no barrier)
    {
      const int b = eb;
      unsigned short hb[4];
      #pragma unroll
      for (int q=0;q<4;q++){
        int dd = ep + q;
        float g_i = gb[b*68 + dd]      + bf2f((unsigned short)(cxi >> (16*q)));
        float g_f = gb[b*68 + 16 + dd] + bf2f((unsigned short)(cxf >> (16*q)));
        float g_g = gb[b*68 + 32 + dd] + bf2f((unsigned short)(cxg >> (16*q)));
        float g_o = gb[b*68 + 48 + dd] + bf2f((unsigned short)(cxo >> (16*q)));
        float c = fsigm(g_f)*cl[b*16+dd] + fsigm(g_i)*ftanh(g_g);
        float h = fsigm(g_o)*ftanh(c);
        cl[b*16+dd] = c;
        hb[q] = f2bf(h);
      }
      unsigned d01 = (unsigned)hb[0] | ((unsigned)hb[1]<<16);
      unsigned d23 = (unsigned)hb[2] | ((unsigned)hb[3]<<16);
      st_blk(hlP, wl, b, kb, d01, d23, (unsigned)(t+1));   // fire-and-forget
      *(unsigned long long*)&hseq[((size_t)t*64 + b)*512 + d0 + ep] =
          (unsigned long long)d01 | ((unsigned long long)d23<<32);
    }
    cxi = nxi; cxf = nxf; cxg = nxg; cxo = nxo;
    // ---- phase B: high cell (only ~8/256 steps) ----
    if (stepflag[t]){
      f32x4 hacc[4] = {};
      // A-operand 1: fresh h_l(t) [gen >= t+1]
      poll_read(hlP + (size_t)wl*paroff + rowoff, (unsigned)(t+1), blk);
      #pragma unroll
      for (int ks=0;ks<16;ks++){
        v128 u; u.u4[0]=blk[ks][0].u4[0]; u.u4[1]=blk[ks][0].u4[1];
                u.u4[2]=blk[ks][1].u4[0]; u.u4[3]=blk[ks][1].u4[1];
        #pragma unroll
        for (int g=0; g<4; g++){
          bf16x8 bi = *(const bf16x8*)&Wihh[(size_t)(g*512 + d0 + lr)*512 + ks*32 + lk*8];
          hacc[g] = __builtin_amdgcn_mfma_f32_16x16x32_bf16(u.h8, bi, hacc[g], 0,0,0);
        }
      }
      // A-operand 2: h_h(current) [gen >= hhneed]
      poll_read(hhP + (size_t)hs*paroff + rowoff, hhneed, blk);
      #pragma unroll
      for (int ks=0;ks<16;ks++){
        v128 u; u.u4[0]=blk[ks][0].u4[0]; u.u4[1]=blk[ks][0].u4[1];
                u.u4[2]=blk[ks][1].u4[0]; u.u4[3]=blk[ks][1].u4[1];
        #pragma unroll
        for (int g=0; g<4; g++){
          bf16x8 bh = *(const bf16x8*)&Whhh[(size_t)(g*512 + d0 + lr)*512 + ks*32 + lk*8];
          hacc[g] = __builtin_amdgcn_mfma_f32_16x16x32_bf16(u.h8, bh, hacc[g], 0,0,0);
        }
      }
      #pragma unroll
      for (int g=0; g<4; g++)
        #pragma unroll
        for (int r=0;r<4;r++){
          int b = mb + lk*4 + r;
          gb[b*68 + g*16 + lr] = hacc[g][r];
        }
      {
        const int b = eb;
        float m = mask[t*64 + b];
        unsigned long long hold4 = ld8_cc(hhP + (size_t)hs*paroff + ((((size_t)b)*128 + kb)<<4));
        unsigned short hn[4];
        #pragma unroll
        for (int q=0;q<4;q++){
          int dd = ep + q; int d = d0 + dd;
          float g_i = gb[b*68+dd]      + bih_high[d]      + bhh_high[d];
          float g_f = gb[b*68+16+dd]   + bih_high[512+d]  + bhh_high[512+d];
          float g_g = gb[b*68+32+dd]   + bih_high[1024+d] + bhh_high[1024+d];
          float g_o = gb[b*68+48+dd]   + bih_high[1536+d] + bhh_high[1536+d];
          float ct = fsigm(g_f)*ch[b*16+dd] + fsigm(g_i)*ftanh(g_g);
          float ht = fsigm(g_o)*ftanh(ct);
          float hold = bf2f((unsigned short)(hold4 >> (16*q)));
          hn[q] = f2bf(m*ht + (1.0f-m)*hold);
          ch[b*16+dd] = m*ct + (1.0f-m)*ch[b*16+dd];
        }
        unsigned d01 = (unsigned)hn[0] | ((unsigned)hn[1]<<16);
        unsigned d23 = (unsigned)hn[2] | ((unsigned)hn[3]<<16);
        st_blk(hhP, hs^1, b, kb, d01, d23, hhneed + 1u);
      }
      // recompute hht from new hh [gen >= hhneed+1]
      poll_read(hhP + (size_t)(hs^1)*paroff + rowoff, hhneed + 1u, blk);
      {
        f32x4 a2[4] = {};
        #pragma unroll
        for (int ks=0;ks<16;ks++){
          v128 u; u.u4[0]=blk[ks][0].u4[0]; u.u4[1]=blk[ks][0].u4[1];
                  u.u4[2]=blk[ks][1].u4[0]; u.u4[3]=blk[ks][1].u4[1];
          #pragma unroll
          for (int g=0; g<4; g++){
            bf16x8 bg = *(const bf16x8*)&Wlh[(size_t)(g*512 + d0 + lr)*512 + ks*32 + lk*8];
            a2[g] = __builtin_amdgcn_mfma_f32_16x16x32_bf16(u.h8, bg, a2[g], 0,0,0);
          }
        }
        #pragma unroll
        for (int g=0; g<4; g++)
          #pragma unroll
          for (int r=0;r<4;r++) hht[(mb + lk*4 + r)*68 + g*16 + lr] = a2[g][r];
      }
      hs ^= 1;
      hhneed += 1u;
    }
  }
  // final states -> f32 (h_l(255) is in parity 0; own blocks only)
  {
    int gi = eb*512 + d0 + ep;
    unsigned long long hl4 = ld8_cc(hlP + ((((size_t)eb)*128 + kb)<<4));
    unsigned long long hh4 = ld8_cc(hhP + (size_t)hs*paroff + ((((size_t)eb)*128 + kb)<<4));
    #pragma unroll
    for (int q=0;q<4;q++){
      outS[gi+q]           = bf2f((unsigned short)(hl4 >> (16*q)));
      outS[32768 + gi + q] = cl[eb*16 + ep + q];
      outS[65536 + gi + q] = bf2f((unsigned short)(hh4 >> (16*q)));
      outS[98304 + gi + q] = ch[eb*16 + ep + q];
    }
  }
}

extern "C" void kernel_launch(void* const* d_in, const int* in_sizes, int n_in,
                              void* d_out, int out_size, void* d_ws, size_t ws_size,
                              hipStream_t stream)
{
  const int*   in0    = (const int*)  d_in[0];
  const int*   in1    = (const int*)  d_in[1];
  const float* hl0    = (const float*)d_in[2];
  const float* cl0    = (const float*)d_in[3];
  const float* hh0    = (const float*)d_in[4];
  const float* ch0    = (const float*)d_in[5];
  const int*   mtok   = (const int*)  d_in[6];
  const float* emb0   = (const float*)d_in[7];
  const float* emb1   = (const float*)d_in[8];
  const float* Wihl_f = (const float*)d_in[9];
  const float* bihl   = (const float*)d_in[10];
  const float* Whhl_f = (const float*)d_in[11];
  const float* bhhl   = (const float*)d_in[12];
  const float* Wihh_f = (const float*)d_in[13];
  const float* bihh   = (const float*)d_in[14];
  const float* Whhh_f = (const float*)d_in[15];
  const float* bhhh   = (const float*)d_in[16];
  const float* Wd0_f  = (const float*)d_in[17];
  const float* bd0    = (const float*)d_in[18];
  const float* Wd1_f  = (const float*)d_in[19];
  const float* bd1    = (const float*)d_in[20];

  // d_out is FLOAT: dec0 [B,T,2048] @0, dec1 [B,T,512] @33554432, states @41943040.
  float* dout = (float*)d_out;
  unsigned short* xW = (unsigned short*)dout;              // 64 MiB scratch in dec0 region
  unsigned short* E  = (unsigned short*)(dout + 33554432); // 16 MiB scratch in dec1 region

  char* ws = (char*)d_ws;
  unsigned short* hseq = (unsigned short*)(ws + 0);          // [16384][512] bf16, 16 MiB
  unsigned short* W0   = (unsigned short*)(ws + 16777216);
  unsigned short* Wlh  = (unsigned short*)(ws + 18874368);
  unsigned short* Whhl = (unsigned short*)(ws + 20971520);
  unsigned short* Wihh = (unsigned short*)(ws + 23068672);
  unsigned short* Whhh = (unsigned short*)(ws + 25165824);
  unsigned short* Wd0  = (unsigned short*)(ws + 27262976);
  unsigned short* Wd1  = (unsigned short*)(ws + 29360128);
  char*           hlP  = ws + 29884416;                      // [2][64][128] 16B gen-blocks, 256KB
  char*           hhP  = ws + 30146560;                      // same, 256KB
  float*          mask = (float*)    (ws + 30408704);        // [256][64]
  unsigned*       sflg = (unsigned*) (ws + 30474240);        // [256]
  unsigned*       bar  = (unsigned*) (ws + 30475264);        // init flags[32*32]

  k_prep<<<2048, 256, 0, stream>>>(in0,in1,mtok,emb0,emb1,Wihl_f,Whhl_f,Wihh_f,Whhh_f,Wd0_f,Wd1_f,
                                   W0,Wlh,Whhl,Wihh,Whhh,Wd0,Wd1,E,mask,sflg,bar,
                                   (uint4v*)hlP,(uint4v*)hhP);
  dim3 g1(128,16);
  k_gemm<<<g1, 256, 0, stream>>>(E, W0, bihl, bhhl, xW, nullptr, 2048, 0);
  k_recur<<<NWG, 256, 0, stream>>>(hl0,cl0,hh0,ch0,bihh,bhhh,xW,Whhl,Wlh,Wihh,Whhh,
                                   mask,sflg,hlP,hhP,hseq,bar,dout + 41943040);
  k_gemm<<<g1, 256, 0, stream>>>(hseq, Wd0, bd0, nullptr, nullptr, dout, 2048, 1);
  dim3 g2(128,4);
  k_gemm<<<g2, 256, 0, stream>>>(hseq, Wd1, bd1, nullptr, nullptr, dout + 33554432, 512, 1);
}